// Round 1
// baseline (648.516 us; speedup 1.0000x reference)
//
#include <hip/hip_runtime.h>
#include <hip/hip_bf16.h>

#define IN_DIM 8192
#define OUT_DIM 16384
#define K_TOP 327

// ---------------- zero the overlap scratch ----------------
__global__ void zero_kernel(int* __restrict__ overlap) {
    int i = blockIdx.x * blockDim.x + threadIdx.x;
    if (i < OUT_DIM) overlap[i] = 0;
}

// ---------------- overlap GEMV: count p>0.5 over active rows ----------------
// grid: (16 col-blocks, 64 row-chunks), 256 threads. Each thread owns 4 columns
// (one float4 per row). Per wave: 64 lanes x 16B = 1KB contiguous per row.
__global__ __launch_bounds__(256) void overlap_kernel(const int* __restrict__ x,
                                                      const float* __restrict__ p,
                                                      int* __restrict__ overlap) {
    constexpr int ROWS = 128;
    __shared__ int rows[ROWS];
    __shared__ int nact_sh;
    const int tid = threadIdx.x;
    const int row0 = blockIdx.y * ROWS;

    if (tid == 0) nact_sh = 0;
    __syncthreads();
    if (tid < ROWS) {
        if (x[row0 + tid] != 0) {
            int idx = atomicAdd(&nact_sh, 1);
            rows[idx] = tid;  // order irrelevant: integer sum commutes
        }
    }
    __syncthreads();
    const int n = nact_sh;

    const int col = blockIdx.x * 1024 + tid * 4;
    const float* pc = p + col;
    int a0 = 0, a1 = 0, a2 = 0, a3 = 0;

    int k = 0;
    for (; k + 1 < n; k += 2) {
        int r1 = rows[k], r2 = rows[k + 1];
        float4 v1 = *(const float4*)(pc + (size_t)(row0 + r1) * OUT_DIM);
        float4 v2 = *(const float4*)(pc + (size_t)(row0 + r2) * OUT_DIM);
        // round-half-even: round(p)==1  <=>  p > 0.5 exactly (0.5 rounds to 0)
        a0 += (v1.x > 0.5f) + (v2.x > 0.5f);
        a1 += (v1.y > 0.5f) + (v2.y > 0.5f);
        a2 += (v1.z > 0.5f) + (v2.z > 0.5f);
        a3 += (v1.w > 0.5f) + (v2.w > 0.5f);
    }
    if (k < n) {
        int r1 = rows[k];
        float4 v1 = *(const float4*)(pc + (size_t)(row0 + r1) * OUT_DIM);
        a0 += (v1.x > 0.5f);
        a1 += (v1.y > 0.5f);
        a2 += (v1.z > 0.5f);
        a3 += (v1.w > 0.5f);
    }
    atomicAdd(&overlap[col + 0], a0);
    atomicAdd(&overlap[col + 1], a1);
    atomicAdd(&overlap[col + 2], a2);
    atomicAdd(&overlap[col + 3], a3);
}

// ---------------- block-wide inclusive prefix scan (1024 threads) ----------------
// Uses wave shuffles (wave=64) + 16-entry LDS for wave totals. After return,
// wsums[15] holds the block-wide total. Costs 2 __syncthreads().
__device__ __forceinline__ int block_scan_incl(int val, int tid, int* wsums) {
    const int lane = tid & 63;
    const int wave = tid >> 6;
    int v = val;
#pragma unroll
    for (int d = 1; d < 64; d <<= 1) {
        int nv = __shfl_up(v, d, 64);
        if (lane >= d) v += nv;
    }
    if (lane == 63) wsums[wave] = v;
    __syncthreads();
    if (wave == 0) {
        int w = (lane < 16) ? wsums[lane] : 0;
#pragma unroll
        for (int d = 1; d < 16; d <<= 1) {
            int nw = __shfl_up(w, d, 64);
            if (lane >= d) w += nw;
        }
        if (lane < 16) wsums[lane] = w;
    }
    __syncthreads();
    int offset = (wave > 0) ? wsums[wave - 1] : 0;
    return v + offset;
}

// ---------------- top-k with lowest-index tie-break ----------------
// Single block, 1024 threads. Histogram over overlap values [0,8192], find
// threshold T (max v with count(>=v) >= K), then accept all >T plus the first
// (K - count(>T)) columns ==T in increasing index order.
#define NB 9216  // 1024 threads * 9 bins, covers [0,8192] with zero padding
__global__ __launch_bounds__(1024) void topk_kernel(const int* __restrict__ overlap,
                                                    float* __restrict__ out) {
    __shared__ int hist[NB];
    __shared__ int wsums[16];
    __shared__ int sh_T;
    __shared__ int sh_R;
    const int tid = threadIdx.x;

    for (int i = tid; i < NB; i += 1024) hist[i] = 0;
    if (tid == 0) sh_T = -1;
    __syncthreads();

    int ov_local[16];
#pragma unroll
    for (int c = 0; c < 16; ++c) {
        int ov = overlap[c * 1024 + tid];
        ov_local[c] = ov;
        atomicAdd(&hist[ov], 1);
    }
    __syncthreads();

    // per-thread chunk of 9 bins
    const int base = tid * 9;
    int h[9];
    int s = 0;
#pragma unroll
    for (int k = 0; k < 9; ++k) {
        h[k] = hist[base + k];
        s += h[k];
    }
    // inclusive prefix of chunk sums -> suffix-exclusive count above this chunk
    int incl = block_scan_incl(s, tid, wsums);
    int total = wsums[15];  // == OUT_DIM
    int suf_excl = total - incl;  // count of overlaps in bins > this chunk

    // find T: max v with csum(v) >= K ; csum(base+k) = suf_excl + sum_{k'>=k} h[k']
    int run = 0;
    int local_T = -1, local_cgt = 0;
#pragma unroll
    for (int k = 8; k >= 0; --k) {
        run += h[k];
        if (local_T < 0 && (suf_excl + run) >= K_TOP) {
            local_T = base + k;
            local_cgt = suf_excl + run - h[k];  // count strictly greater than T
        }
    }
    __syncthreads();  // hist reads done before any reuse; also orders sh_T init
    if (local_T >= 0) atomicMax(&sh_T, local_T);
    __syncthreads();
    const int T = sh_T;
    if (local_T == T && local_T >= 0) sh_R = K_TOP - local_cgt;  // ties to accept
    __syncthreads();
    const int R = sh_R;

    // selection: chunks in increasing column order; prefix of (==T) flags gives
    // each tied column its rank; accept ranks < R (lowest indices first).
    int running = 0;
#pragma unroll
    for (int c = 0; c < 16; ++c) {
        int ov = ov_local[c];
        int flag = (ov == T) ? 1 : 0;
        int pincl = block_scan_incl(flag, tid, wsums);
        int pexcl = pincl - flag;
        int sel = (ov > T) || (flag && (running + pexcl) < R);
        out[c * 1024 + tid] = sel ? 1.0f : 0.0f;
        running += wsums[15];
        __syncthreads();  // protect wsums before next scan overwrites
    }
}

extern "C" void kernel_launch(void* const* d_in, const int* in_sizes, int n_in,
                              void* d_out, int out_size, void* d_ws, size_t ws_size,
                              hipStream_t stream) {
    const int* x = (const int*)d_in[0];
    const float* p = (const float*)d_in[1];
    float* out = (float*)d_out;
    int* overlap = (int*)d_ws;  // 16384 ints = 64 KB

    zero_kernel<<<64, 256, 0, stream>>>(overlap);
    overlap_kernel<<<dim3(16, 64), 256, 0, stream>>>(x, p, overlap);
    topk_kernel<<<1, 1024, 0, stream>>>(overlap, out);
}

// Round 2
// 628.677 us; speedup vs baseline: 1.0316x; 1.0316x over previous
//
#include <hip/hip_runtime.h>
#include <hip/hip_bf16.h>

#define IN_DIM 8192
#define OUT_DIM 16384
#define K_TOP 327
#define ROW_CHUNKS 64
#define ROWS_PER_CHUNK 128  // ROW_CHUNKS * ROWS_PER_CHUNK == IN_DIM

typedef float vf4 __attribute__((ext_vector_type(4)));

// ---------------- overlap GEMV partials: count p>0.5 over active rows --------
// grid: (16 col-blocks, 64 row-chunks), 256 threads. Each thread owns 4 columns
// (one 16B load per row). No atomics: each row-chunk writes its own 64KB
// partial array; a tiny reduce kernel sums them.
__global__ __launch_bounds__(256) void overlap_kernel(const int* __restrict__ x,
                                                      const float* __restrict__ p,
                                                      int* __restrict__ partial) {
    __shared__ int rows[ROWS_PER_CHUNK];
    __shared__ int nact_sh;
    const int tid = threadIdx.x;
    const int row0 = blockIdx.y * ROWS_PER_CHUNK;

    if (tid == 0) nact_sh = 0;
    __syncthreads();
    if (tid < ROWS_PER_CHUNK) {
        if (x[row0 + tid] != 0) {
            rows[atomicAdd(&nact_sh, 1)] = tid;  // order irrelevant: sum commutes
        }
    }
    __syncthreads();
    const int n = nact_sh;

    const int col = blockIdx.x * 1024 + tid * 4;
    const float* pc = p + (size_t)row0 * OUT_DIM + col;
    int a0 = 0, a1 = 0, a2 = 0, a3 = 0;

    int k = 0;
    for (; k + 3 < n; k += 4) {  // 4 loads in flight: 4KB/wave MLP
        int r0 = rows[k], r1 = rows[k + 1], r2 = rows[k + 2], r3 = rows[k + 3];
        vf4 v0 = __builtin_nontemporal_load((const vf4*)(pc + (size_t)r0 * OUT_DIM));
        vf4 v1 = __builtin_nontemporal_load((const vf4*)(pc + (size_t)r1 * OUT_DIM));
        vf4 v2 = __builtin_nontemporal_load((const vf4*)(pc + (size_t)r2 * OUT_DIM));
        vf4 v3 = __builtin_nontemporal_load((const vf4*)(pc + (size_t)r3 * OUT_DIM));
        // round-half-even: round(p)==1  <=>  p > 0.5 strictly (0.5 rounds to 0)
        a0 += (v0.x > 0.5f) + (v1.x > 0.5f) + (v2.x > 0.5f) + (v3.x > 0.5f);
        a1 += (v0.y > 0.5f) + (v1.y > 0.5f) + (v2.y > 0.5f) + (v3.y > 0.5f);
        a2 += (v0.z > 0.5f) + (v1.z > 0.5f) + (v2.z > 0.5f) + (v3.z > 0.5f);
        a3 += (v0.w > 0.5f) + (v1.w > 0.5f) + (v2.w > 0.5f) + (v3.w > 0.5f);
    }
    for (; k < n; ++k) {
        int r = rows[k];
        vf4 v = __builtin_nontemporal_load((const vf4*)(pc + (size_t)r * OUT_DIM));
        a0 += (v.x > 0.5f);
        a1 += (v.y > 0.5f);
        a2 += (v.z > 0.5f);
        a3 += (v.w > 0.5f);
    }
    // unconditional store (also covers n==0), so no zero-init pass is needed
    int* o = partial + (size_t)blockIdx.y * OUT_DIM + col;
    o[0] = a0; o[1] = a1; o[2] = a2; o[3] = a3;
}

// ---------------- sum the 64 partial arrays into overlap ----------------
__global__ __launch_bounds__(256) void reduce_kernel(const int* __restrict__ partial,
                                                     int* __restrict__ overlap) {
    const int t = blockIdx.x * 256 + threadIdx.x;  // 64 blocks -> 16384 threads
    int s = 0;
#pragma unroll
    for (int c = 0; c < ROW_CHUNKS; ++c) s += partial[(size_t)c * OUT_DIM + t];
    overlap[t] = s;
}

// ---------------- block-wide inclusive prefix scan (1024 threads) ------------
// wave=64 shuffles + 16-entry LDS for wave totals. wsums[15] = block total.
__device__ __forceinline__ int block_scan_incl(int val, int tid, int* wsums) {
    const int lane = tid & 63;
    const int wave = tid >> 6;
    int v = val;
#pragma unroll
    for (int d = 1; d < 64; d <<= 1) {
        int nv = __shfl_up(v, d, 64);
        if (lane >= d) v += nv;
    }
    if (lane == 63) wsums[wave] = v;
    __syncthreads();
    if (wave == 0) {
        int w = (lane < 16) ? wsums[lane] : 0;
#pragma unroll
        for (int d = 1; d < 16; d <<= 1) {
            int nw = __shfl_up(w, d, 64);
            if (lane >= d) w += nw;
        }
        if (lane < 16) wsums[lane] = w;
    }
    __syncthreads();
    return v + ((wave > 0) ? wsums[wave - 1] : 0);
}

// ---------------- top-k with lowest-index tie-break ----------------
// Single block, 1024 threads. Histogram over [0,8192], threshold T = max v with
// count(>=v) >= K; accept all >T plus first (K - count(>T)) cols ==T by index.
#define NB 9216  // 1024 threads * 9 bins
__global__ __launch_bounds__(1024) void topk_kernel(const int* __restrict__ overlap,
                                                    float* __restrict__ out) {
    __shared__ int hist[NB];
    __shared__ int wsums[16];
    __shared__ int sh_T;
    __shared__ int sh_R;
    const int tid = threadIdx.x;

    for (int i = tid; i < NB; i += 1024) hist[i] = 0;
    if (tid == 0) sh_T = -1;
    __syncthreads();

    int ov_local[16];
#pragma unroll
    for (int c = 0; c < 16; ++c) {
        int ov = overlap[c * 1024 + tid];
        ov_local[c] = ov;
        atomicAdd(&hist[ov], 1);
    }
    __syncthreads();

    const int base = tid * 9;
    int h[9];
    int s = 0;
#pragma unroll
    for (int k = 0; k < 9; ++k) {
        h[k] = hist[base + k];
        s += h[k];
    }
    int incl = block_scan_incl(s, tid, wsums);
    int total = wsums[15];
    int suf_excl = total - incl;  // count in bins above this thread's chunk

    int run = 0;
    int local_T = -1, local_cgt = 0;
#pragma unroll
    for (int k = 8; k >= 0; --k) {
        run += h[k];
        if (local_T < 0 && (suf_excl + run) >= K_TOP) {
            local_T = base + k;
            local_cgt = suf_excl + run - h[k];  // strictly-greater count
        }
    }
    __syncthreads();
    if (local_T >= 0) atomicMax(&sh_T, local_T);
    __syncthreads();
    const int T = sh_T;
    if (local_T == T && local_T >= 0) sh_R = K_TOP - local_cgt;
    __syncthreads();
    const int R = sh_R;

    int running = 0;
#pragma unroll
    for (int c = 0; c < 16; ++c) {
        int ov = ov_local[c];
        int flag = (ov == T) ? 1 : 0;
        int pincl = block_scan_incl(flag, tid, wsums);
        int pexcl = pincl - flag;
        int sel = (ov > T) || (flag && (running + pexcl) < R);
        out[c * 1024 + tid] = sel ? 1.0f : 0.0f;
        running += wsums[15];
        __syncthreads();
    }
}

extern "C" void kernel_launch(void* const* d_in, const int* in_sizes, int n_in,
                              void* d_out, int out_size, void* d_ws, size_t ws_size,
                              hipStream_t stream) {
    const int* x = (const int*)d_in[0];
    const float* p = (const float*)d_in[1];
    float* out = (float*)d_out;
    int* partial = (int*)d_ws;                          // 64*16384 ints = 4 MB
    int* overlap = (int*)d_ws + ROW_CHUNKS * OUT_DIM;   // 64 KB

    overlap_kernel<<<dim3(16, ROW_CHUNKS), 256, 0, stream>>>(x, p, partial);
    reduce_kernel<<<ROW_CHUNKS, 256, 0, stream>>>(partial, overlap);
    topk_kernel<<<1, 1024, 0, stream>>>(overlap, out);
}

// Round 3
// 620.583 us; speedup vs baseline: 1.0450x; 1.0130x over previous
//
#include <hip/hip_runtime.h>
#include <hip/hip_bf16.h>

#define IN_DIM 8192
#define OUT_DIM 16384
#define K_TOP 327
#define ROW_CHUNKS 64
#define ROWS_PER_CHUNK 128  // ROW_CHUNKS * ROWS_PER_CHUNK == IN_DIM

typedef float vf4 __attribute__((ext_vector_type(4)));

// ---------------- overlap GEMV partials: count p>0.5 over active rows --------
// grid: (16 col-blocks, 64 row-chunks), 256 threads. Each thread owns 4 columns
// (one 16B load per row), unroll-8 -> 128B/thread in flight. No atomics: each
// row-chunk writes its own 64KB partial slice; reduce_kernel sums them.
__global__ __launch_bounds__(256) void overlap_kernel(const int* __restrict__ x,
                                                      const float* __restrict__ p,
                                                      int* __restrict__ partial) {
    __shared__ int rows[ROWS_PER_CHUNK];
    __shared__ int nact_sh;
    const int tid = threadIdx.x;
    const int row0 = blockIdx.y * ROWS_PER_CHUNK;

    if (tid == 0) nact_sh = 0;
    __syncthreads();
    if (tid < ROWS_PER_CHUNK) {
        if (x[row0 + tid] != 0) {
            rows[atomicAdd(&nact_sh, 1)] = tid;  // order irrelevant: sum commutes
        }
    }
    __syncthreads();
    const int n = nact_sh;

    const int col = blockIdx.x * 1024 + tid * 4;
    const float* pc = p + (size_t)row0 * OUT_DIM + col;
    int a0 = 0, a1 = 0, a2 = 0, a3 = 0;

    int k = 0;
    for (; k + 7 < n; k += 8) {  // 8 loads in flight per thread
        vf4 v[8];
#pragma unroll
        for (int j = 0; j < 8; ++j)
            v[j] = __builtin_nontemporal_load((const vf4*)(pc + (size_t)rows[k + j] * OUT_DIM));
        // round-half-even: round(p)==1  <=>  p > 0.5 strictly (0.5 rounds to 0)
#pragma unroll
        for (int j = 0; j < 8; ++j) {
            a0 += (v[j].x > 0.5f);
            a1 += (v[j].y > 0.5f);
            a2 += (v[j].z > 0.5f);
            a3 += (v[j].w > 0.5f);
        }
    }
    for (; k < n; ++k) {
        vf4 v = __builtin_nontemporal_load((const vf4*)(pc + (size_t)rows[k] * OUT_DIM));
        a0 += (v.x > 0.5f);
        a1 += (v.y > 0.5f);
        a2 += (v.z > 0.5f);
        a3 += (v.w > 0.5f);
    }
    // unconditional store (also covers n==0), so no zero-init pass is needed
    int* o = partial + (size_t)blockIdx.y * OUT_DIM + col;
    o[0] = a0; o[1] = a1; o[2] = a2; o[3] = a3;
}

// ---------------- sum the 64 partial arrays into overlap ----------------
__global__ __launch_bounds__(256) void reduce_kernel(const int* __restrict__ partial,
                                                     int* __restrict__ overlap) {
    const int t = blockIdx.x * 256 + threadIdx.x;  // 64 blocks -> 16384 threads
    int s = 0;
#pragma unroll
    for (int c = 0; c < ROW_CHUNKS; ++c) s += partial[(size_t)c * OUT_DIM + t];
    overlap[t] = s;
}

// ---------------- block-wide inclusive prefix scan (1024 threads) ------------
// wave=64 shuffles + 16-entry LDS for wave totals. wsums[15] = block total.
__device__ __forceinline__ int block_scan_incl(int val, int tid, int* wsums) {
    const int lane = tid & 63;
    const int wave = tid >> 6;
    int v = val;
#pragma unroll
    for (int d = 1; d < 64; d <<= 1) {
        int nv = __shfl_up(v, d, 64);
        if (lane >= d) v += nv;
    }
    if (lane == 63) wsums[wave] = v;
    __syncthreads();
    if (wave == 0) {
        int w = (lane < 16) ? wsums[lane] : 0;
#pragma unroll
        for (int d = 1; d < 16; d <<= 1) {
            int nw = __shfl_up(w, d, 64);
            if (lane >= d) w += nw;
        }
        if (lane < 16) wsums[lane] = w;
    }
    __syncthreads();
    return v + ((wave > 0) ? wsums[wave - 1] : 0);
}

// ---------------- top-k with lowest-index tie-break ----------------
// Single block, 1024 threads. Each thread owns 16 CONTIGUOUS columns
// [tid*16, tid*16+16), so global column order == (tid, local) order and the
// tie-ranking needs only ONE block scan. Histogram over [0,8192] finds
// T = max v with count(>=v) >= K; accept all >T plus first (K - count(>T))
// columns ==T in increasing index order.
#define NB 9216  // 1024 threads * 9 bins, covers [0,8192]
__global__ __launch_bounds__(1024) void topk_kernel(const int* __restrict__ overlap,
                                                    float* __restrict__ out) {
    __shared__ int hist[NB];
    __shared__ int wsums[16];
    __shared__ int sh_T;
    __shared__ int sh_R;
    const int tid = threadIdx.x;

    for (int i = tid; i < NB; i += 1024) hist[i] = 0;
    if (tid == 0) sh_T = -1;
    __syncthreads();

    // vectorized load of this thread's 16 contiguous overlap values
    int ov[16];
    const int4* ovp = (const int4*)(overlap + tid * 16);
#pragma unroll
    for (int q = 0; q < 4; ++q) {
        int4 v = ovp[q];
        ov[4 * q + 0] = v.x; ov[4 * q + 1] = v.y;
        ov[4 * q + 2] = v.z; ov[4 * q + 3] = v.w;
    }
#pragma unroll
    for (int c = 0; c < 16; ++c) atomicAdd(&hist[ov[c]], 1);
    __syncthreads();

    // threshold: per-thread chunk of 9 bins
    const int base = tid * 9;
    int h[9];
    int s = 0;
#pragma unroll
    for (int k = 0; k < 9; ++k) {
        h[k] = hist[base + k];
        s += h[k];
    }
    int incl = block_scan_incl(s, tid, wsums);
    int total = wsums[15];
    int suf_excl = total - incl;  // count of values in bins above this chunk

    int run = 0;
    int local_T = -1, local_cgt = 0;
#pragma unroll
    for (int k = 8; k >= 0; --k) {
        run += h[k];
        if (local_T < 0 && (suf_excl + run) >= K_TOP) {
            local_T = base + k;                  // max v in chunk w/ count(>=v)>=K
            local_cgt = suf_excl + run - h[k];   // count strictly greater than v
        }
    }
    __syncthreads();
    if (local_T >= 0) atomicMax(&sh_T, local_T);
    __syncthreads();
    const int T = sh_T;
    if (local_T == T && local_T >= 0) sh_R = K_TOP - local_cgt;  // ties to accept
    __syncthreads();
    const int R = sh_R;

    // single scan: per-thread count of ==T -> exclusive rank offset
    int nflag = 0;
#pragma unroll
    for (int c = 0; c < 16; ++c) nflag += (ov[c] == T);
    int incl2 = block_scan_incl(nflag, tid, wsums);
    int rank = incl2 - nflag;  // global index-ordered rank of this thread's first tie

    float res[16];
#pragma unroll
    for (int c = 0; c < 16; ++c) {
        int f = (ov[c] == T);
        int sel = (ov[c] > T) || (f && rank < R);
        rank += f;
        res[c] = sel ? 1.0f : 0.0f;
    }
    vf4* op = (vf4*)(out + tid * 16);
#pragma unroll
    for (int q = 0; q < 4; ++q) {
        vf4 w;
        w.x = res[4 * q + 0]; w.y = res[4 * q + 1];
        w.z = res[4 * q + 2]; w.w = res[4 * q + 3];
        op[q] = w;
    }
}

extern "C" void kernel_launch(void* const* d_in, const int* in_sizes, int n_in,
                              void* d_out, int out_size, void* d_ws, size_t ws_size,
                              hipStream_t stream) {
    const int* x = (const int*)d_in[0];
    const float* p = (const float*)d_in[1];
    float* out = (float*)d_out;
    int* partial = (int*)d_ws;                          // 64*16384 ints = 4 MB
    int* overlap = (int*)d_ws + ROW_CHUNKS * OUT_DIM;   // 64 KB

    overlap_kernel<<<dim3(16, ROW_CHUNKS), 256, 0, stream>>>(x, p, partial);
    reduce_kernel<<<ROW_CHUNKS, 256, 0, stream>>>(partial, overlap);
    topk_kernel<<<1, 1024, 0, stream>>>(overlap, out);
}